// Round 6
// baseline (3335.377 us; speedup 1.0000x reference)
//
#include <hip/hip_runtime.h>

#define HH 720
#define WW 1280
#define HWP (HH*WW)

static constexpr int NFRM = 4;
typedef _Float16 h2 __attribute__((ext_vector_type(2)));
typedef _Float16 h4 __attribute__((ext_vector_type(4)));

// ================= register-tiled 3x3 SAME conv: PX px/thread, frame-batched =================
template <int PX, int C0, int C1, int COUT, bool RELU>
__global__ __launch_bounds__(128) void conv3x3_v3(const float* __restrict__ in0, long i0fs,
                                                  const float* __restrict__ in1, long i1fs,
                                                  const float* __restrict__ w,
                                                  const float* __restrict__ b,
                                                  float* __restrict__ out, long ofs) {
  constexpr int CIN = C0 + C1;
  constexpr int NBX = WW / (16 * PX);
  int fi = blockIdx.y;
  in0 += (size_t)fi * i0fs;
  out += (size_t)fi * ofs;
  const float* in1f = nullptr;
  if constexpr (C1 > 0) in1f = in1 + (size_t)fi * i1fs;

  int bx = blockIdx.x % NBX;
  int by = blockIdx.x / NBX;
  int tx = threadIdx.x & 15;
  int ty = threadIdx.x >> 4;
  int gx0 = bx * (16 * PX) + tx * PX;
  int gy  = by * 8 + ty;

  float acc[COUT][PX];
  #pragma unroll
  for (int co = 0; co < COUT; ++co) {
    float bv = b[co];
    #pragma unroll
    for (int px = 0; px < PX; ++px) acc[co][px] = bv;
  }

  const bool lok = (gx0 > 0);
  const bool rok = (gx0 + PX < WW);

  for (int c = 0; c < CIN; ++c) {
    const float* ch;
    if constexpr (C1 > 0)
      ch = (c < C0) ? (in0 + (size_t)c * HWP) : (in1f + (size_t)(c - C0) * HWP);
    else
      ch = in0 + (size_t)c * HWP;
    float r[3][PX + 2];
    #pragma unroll
    for (int ky = 0; ky < 3; ++ky) {
      int iy = gy + ky - 1;
      bool yok = (iy >= 0) && (iy < HH);
      const float* row = ch + (ptrdiff_t)iy * WW;
      #pragma unroll
      for (int j = 0; j < PX / 4; ++j) {
        float4 a = yok ? *reinterpret_cast<const float4*>(row + gx0 + 4 * j)
                       : make_float4(0.f, 0.f, 0.f, 0.f);
        r[ky][1 + 4*j + 0] = a.x; r[ky][1 + 4*j + 1] = a.y;
        r[ky][1 + 4*j + 2] = a.z; r[ky][1 + 4*j + 3] = a.w;
      }
      r[ky][0]      = (yok && lok) ? row[gx0 - 1]  : 0.f;
      r[ky][PX + 1] = (yok && rok) ? row[gx0 + PX] : 0.f;
    }
    #pragma unroll
    for (int co = 0; co < COUT; ++co) {
      #pragma unroll
      for (int ky = 0; ky < 3; ++ky) {
        #pragma unroll
        for (int kx = 0; kx < 3; ++kx) {
          float wv = w[((co * CIN + c) * 3 + ky) * 3 + kx];
          #pragma unroll
          for (int px = 0; px < PX; ++px)
            acc[co][px] = fmaf(wv, r[ky][px + kx], acc[co][px]);
        }
      }
    }
  }

  size_t p = (size_t)gy * WW + gx0;
  #pragma unroll
  for (int co = 0; co < COUT; ++co) {
    #pragma unroll
    for (int j = 0; j < PX / 4; ++j) {
      float4 o;
      o.x = RELU ? fmaxf(acc[co][4*j+0], 0.f) : acc[co][4*j+0];
      o.y = RELU ? fmaxf(acc[co][4*j+1], 0.f) : acc[co][4*j+1];
      o.z = RELU ? fmaxf(acc[co][4*j+2], 0.f) : acc[co][4*j+2];
      o.w = RELU ? fmaxf(acc[co][4*j+3], 0.f) : acc[co][4*j+3];
      *reinterpret_cast<float4*>(out + (size_t)co * HWP + p + 4*j) = o;
    }
  }
}

// ================= LCN: out = [lcn(color), color] (6 planes), 8 px/thread, frame-batched =================
__global__ __launch_bounds__(128) void lcn_v3(const float* __restrict__ x, long ifs,
                                              float* __restrict__ out, long ofs) {
  constexpr int NBX = WW / 128;
  int fi = blockIdx.y;
  const float* color = x + (size_t)fi * ifs;
  out += (size_t)fi * ofs;
  int bx = blockIdx.x % NBX;
  int by = blockIdx.x / NBX;
  int tx = threadIdx.x & 15;
  int ty = threadIdx.x >> 4;
  int gx0 = bx * 128 + tx * 8;
  int gy  = by * 8 + ty;
  const bool lok = (gx0 > 0);
  const bool rok = (gx0 + 8 < WW);
  size_t p = (size_t)gy * WW + gx0;

  #pragma unroll
  for (int c = 0; c < 3; ++c) {
    const float* ch = color + (size_t)c * HWP;
    float r[3][10];
    #pragma unroll
    for (int ky = 0; ky < 3; ++ky) {
      int iy = gy + ky - 1;
      bool yok = (iy >= 0) && (iy < HH);
      const float* row = ch + (ptrdiff_t)iy * WW;
      float4 a = yok ? *reinterpret_cast<const float4*>(row + gx0)
                     : make_float4(0.f, 0.f, 0.f, 0.f);
      float4 q = yok ? *reinterpret_cast<const float4*>(row + gx0 + 4)
                     : make_float4(0.f, 0.f, 0.f, 0.f);
      r[ky][0] = (yok && lok) ? row[gx0 - 1] : 0.f;
      r[ky][1] = a.x; r[ky][2] = a.y; r[ky][3] = a.z; r[ky][4] = a.w;
      r[ky][5] = q.x; r[ky][6] = q.y; r[ky][7] = q.z; r[ky][8] = q.w;
      r[ky][9] = (yok && rok) ? row[gx0 + 8] : 0.f;
    }
    float lcnv[8], cv[8];
    #pragma unroll
    for (int px = 0; px < 8; ++px) {
      float s = 0.f, s2 = 0.f;
      #pragma unroll
      for (int ky = 0; ky < 3; ++ky)
        #pragma unroll
        for (int kx = 0; kx < 3; ++kx) {
          float v = r[ky][px + kx];
          s += v; s2 = fmaf(v, v, s2);
        }
      float mean = s * (1.f / 9.f);
      float mean2 = s2 * (1.f / 9.f);
      float var = fmaxf(mean2 - mean * mean, 0.f);
      cv[px] = r[1][px + 1];
      lcnv[px] = (cv[px] - mean) * rsqrtf(var + 1e-5f);
    }
    #pragma unroll
    for (int h = 0; h < 2; ++h) {
      float4 o0 = make_float4(lcnv[4*h+0], lcnv[4*h+1], lcnv[4*h+2], lcnv[4*h+3]);
      float4 o1 = make_float4(cv[4*h+0], cv[4*h+1], cv[4*h+2], cv[4*h+3]);
      *reinterpret_cast<float4*>(out + (size_t)c * HWP + p + 4*h) = o0;
      *reinterpret_cast<float4*>(out + (size_t)(3 + c) * HWP + p + 4*h) = o1;
    }
  }
}

// ================= temporal blend: dyn = a*[color,hid] + (1-a)*temporal =================
__global__ __launch_bounds__(256) void blend_v3(const float* __restrict__ color,
                                                const float* __restrict__ hid,
                                                const float* __restrict__ temporal,
                                                const float* __restrict__ alpha,
                                                float* __restrict__ dyn, int first) {
  int i = (blockIdx.x * 256 + threadIdx.x) * 4;
  if (i >= HWP) return;
  if (first) {
    #pragma unroll
    for (int c = 0; c < 3; ++c)
      *reinterpret_cast<float4*>(dyn + (size_t)c * HWP + i) =
          *reinterpret_cast<const float4*>(color + (size_t)c * HWP + i);
    *reinterpret_cast<float4*>(dyn + 3 * (size_t)HWP + i) =
        *reinterpret_cast<const float4*>(hid + i);
  } else {
    float a = alpha[0];
    float om = 1.f - a;
    #pragma unroll
    for (int c = 0; c < 4; ++c) {
      const float* src = (c < 3) ? (color + (size_t)c * HWP) : hid;
      float4 cv = *reinterpret_cast<const float4*>(src + i);
      float4 tv = *reinterpret_cast<const float4*>(temporal + (size_t)c * HWP + i);
      float4 o;
      o.x = a * cv.x + om * tv.x;
      o.y = a * cv.y + om * tv.y;
      o.z = a * cv.z + om * tv.z;
      o.w = a * cv.w + om * tv.w;
      *reinterpret_cast<float4*>(dyn + (size_t)c * HWP + i) = o;
    }
  }
}

// ====== fused filter stage: 13->8 conv (in LDS) + bilateral 7x7, tile 32x16, 256 thr ======
#define FBC 38              // feat/dyn region cols
#define FBR 22              // feat/dyn region rows
#define FBPAD 840
#define INW 40              // conv-input region cols
#define INH 24              // conv-input region rows
#define INPLANE (INW*INH)   // 960

__device__ __forceinline__ int bswz(int lin) { return lin ^ ((lin >> 3) & 7); }
__device__ __forceinline__ unsigned pkh(float a, float b) {
  return __builtin_bit_cast(unsigned, __builtin_amdgcn_cvt_pkrtz(a, b));
}

template <bool OUT>
__global__ __launch_bounds__(256, 3) void filt_fused(
    const float* __restrict__ cur,     // 4 planes (dyn)
    const float* __restrict__ fixedp,  // 9 planes
    const float* __restrict__ wconv,   // 8x13x3x3
    const float* __restrict__ bias,    // 8
    const float* __restrict__ scale,   // 8
    float* __restrict__ outdyn,        // 4 planes
    const float* __restrict__ albedo,  // 3 planes (OUT only)
    float* __restrict__ outp)          // 3 planes (OUT only)
{
  __shared__ _Float16 pin[13 * INPLANE + 8];
  __shared__ uint4  ft[FBPAD];
  __shared__ float4 dt[FBPAD];
  const int bx = blockIdx.x % 40;
  const int by = blockIdx.x / 40;
  const int X0 = bx * 32, Y0 = by * 16;
  const int tid = threadIdx.x;

  // ---- phase 1: stage 13 planes (zero-padded, f16 planar), region origin (X0-4, Y0-4)
  for (int i = tid; i < 13 * INH * (INW / 2); i += 256) {
    int c   = i / (INH * (INW / 2));
    int rem = i - c * (INH * (INW / 2));
    int iy  = rem / (INW / 2);
    int ix  = (rem - iy * (INW / 2)) * 2;
    int gy = Y0 - 4 + iy;
    int gx = X0 - 4 + ix;
    const float* src = (c < 4) ? (cur + (size_t)c * HWP) : (fixedp + (size_t)(c - 4) * HWP);
    float v0 = 0.f, v1 = 0.f;
    if (gy >= 0 && gy < HH) {
      const float* row = src + (size_t)gy * WW;
      if (gx >= 0 && gx + 1 < WW) {
        float2 t = *reinterpret_cast<const float2*>(row + gx);
        v0 = t.x; v1 = t.y;
      } else {
        if (gx >= 0 && gx < WW) v0 = row[gx];
        if (gx + 1 >= 0 && gx + 1 < WW) v1 = row[gx + 1];
      }
    }
    h2 hv; hv[0] = (_Float16)v0; hv[1] = (_Float16)v1;
    *reinterpret_cast<h2*>(&pin[c * INPLANE + iy * INW + ix]) = hv;
  }
  __syncthreads();

  // ---- phase 2: conv 13->8 over FT region (zero-pad SAME, edge-clamped sampling) + dt repack
  const bool interior = (bx > 0) && (bx < 39) && (by > 0) && (by < 44);
  const int xlo = 0 - (X0 - 3), xhi = (WW - 1) - (X0 - 3);
  const int ylo = 0 - (Y0 - 3), yhi = (HH - 1) - (Y0 - 3);
  {
    int ctx = tid % 10, cty = tid / 10;
    if (cty < FBR) {
      int fx0 = ctx * 4;
      float acc[8][4];
      #pragma unroll
      for (int co = 0; co < 8; ++co) {
        float bv = bias[co];
        acc[co][0] = bv; acc[co][1] = bv; acc[co][2] = bv; acc[co][3] = bv;
      }
      int fyc = min(max(cty, ylo), yhi);
      if (interior) {
        for (int ci = 0; ci < 13; ++ci) {
          #pragma unroll
          for (int ky = 0; ky < 3; ++ky) {
            const _Float16* rp = &pin[ci * INPLANE + (cty + ky) * INW + fx0];
            h4 a = *reinterpret_cast<const h4*>(rp);
            h4 b = *reinterpret_cast<const h4*>(rp + 4);
            float rr[6] = {(float)a[0], (float)a[1], (float)a[2], (float)a[3],
                           (float)b[0], (float)b[1]};
            #pragma unroll
            for (int co = 0; co < 8; ++co) {
              const float* wp = &wconv[((co * 13 + ci) * 3 + ky) * 3];
              float w0 = wp[0], w1 = wp[1], w2 = wp[2];
              #pragma unroll
              for (int px = 0; px < 4; ++px)
                acc[co][px] = fmaf(w0, rr[px], fmaf(w1, rr[px + 1], fmaf(w2, rr[px + 2], acc[co][px])));
            }
          }
        }
      } else {
        for (int ci = 0; ci < 13; ++ci) {
          #pragma unroll
          for (int ky = 0; ky < 3; ++ky) {
            const _Float16* rp = &pin[ci * INPLANE + (fyc + ky) * INW];
            #pragma unroll
            for (int px = 0; px < 4; ++px) {
              int fxc = min(max(fx0 + px, xlo), xhi);
              float r0 = (float)rp[fxc], r1 = (float)rp[fxc + 1], r2 = (float)rp[fxc + 2];
              #pragma unroll
              for (int co = 0; co < 8; ++co) {
                const float* wp = &wconv[((co * 13 + ci) * 3 + ky) * 3];
                acc[co][px] = fmaf(wp[0], r0, fmaf(wp[1], r1, fmaf(wp[2], r2, acc[co][px])));
              }
            }
          }
        }
      }
      #pragma unroll
      for (int px = 0; px < 4; ++px) {
        int fx = fx0 + px;
        if (fx < FBC) {
          int wsl = bswz(cty * FBC + fx);
          uint4 u;
          u.x = pkh(acc[0][px], acc[1][px]);
          u.y = pkh(acc[2][px], acc[3][px]);
          u.z = pkh(acc[4][px], acc[5][px]);
          u.w = pkh(acc[6][px], acc[7][px]);
          ft[wsl] = u;
          int fxc = min(max(fx, xlo), xhi);
          int ii = (fyc + 1) * INW + (fxc + 1);
          float4 d;
          d.x = (float)pin[0 * INPLANE + ii];
          d.y = (float)pin[1 * INPLANE + ii];
          d.z = (float)pin[2 * INPLANE + ii];
          d.w = (float)pin[3 * INPLANE + ii];
          dt[wsl] = d;
        }
      }
    }
  }
  __syncthreads();

  // ---- phase 3: bilateral 7x7, 2 px/thread
  int txg = tid & 15;
  int ty  = tid >> 4;

  float sv[8];
  #pragma unroll
  for (int c = 0; c < 8; ++c) sv[c] = scale[c];

  float sfc[2][8], A[2];
  #pragma unroll
  for (int p = 0; p < 2; ++p) {
    int lin = (ty + 3) * FBC + txg * 2 + 3 + p;
    uint4 u = ft[bswz(lin)];
    h2 a0 = __builtin_bit_cast(h2, u.x), a1 = __builtin_bit_cast(h2, u.y);
    h2 a2 = __builtin_bit_cast(h2, u.z), a3 = __builtin_bit_cast(h2, u.w);
    float fc[8] = {(float)a0[0], (float)a0[1], (float)a1[0], (float)a1[1],
                   (float)a2[0], (float)a2[1], (float)a3[0], (float)a3[1]};
    float aa = 0.f;
    #pragma unroll
    for (int c = 0; c < 8; ++c) {
      sfc[p][c] = sv[c] * fc[c];
      aa = fmaf(sfc[p][c], fc[c], aa);
    }
    A[p] = aa;
  }

  float acc[2][4], ws2[2];
  #pragma unroll
  for (int p = 0; p < 2; ++p) {
    ws2[p] = 0.f;
    acc[p][0] = acc[p][1] = acc[p][2] = acc[p][3] = 0.f;
  }

  for (int dy = 0; dy < 7; ++dy) {
    int rowb = (ty + dy) * FBC + txg * 2;
    #pragma unroll
    for (int dx = 0; dx < 8; ++dx) {
      int w = bswz(rowb + dx);
      float4 dv = dt[w];
      uint4 u = ft[w];
      h2 a0 = __builtin_bit_cast(h2, u.x), a1 = __builtin_bit_cast(h2, u.y);
      h2 a2 = __builtin_bit_cast(h2, u.z), a3 = __builtin_bit_cast(h2, u.w);
      float f[8] = {(float)a0[0], (float)a0[1], (float)a1[0], (float)a1[1],
                    (float)a2[0], (float)a2[1], (float)a3[0], (float)a3[1]};
      float B = 0.f;
      #pragma unroll
      for (int c = 0; c < 8; ++c) B = fmaf(sv[c] * f[c], f[c], B);
      #pragma unroll
      for (int p = 0; p < 2; ++p) {
        if (dx - p >= 0 && dx - p <= 6) {
          float C = 0.f;
          #pragma unroll
          for (int c = 0; c < 8; ++c) C = fmaf(sfc[p][c], f[c], C);
          float e = fmaf(-2.f, C, A[p] + B);
          float wgt = __expf(-e);
          acc[p][0] = fmaf(wgt, dv.x, acc[p][0]);
          acc[p][1] = fmaf(wgt, dv.y, acc[p][1]);
          acc[p][2] = fmaf(wgt, dv.z, acc[p][2]);
          acc[p][3] = fmaf(wgt, dv.w, acc[p][3]);
          ws2[p] += wgt;
        }
      }
    }
  }

  int gy = Y0 + ty;
  int gx0 = X0 + txg * 2;
  size_t p0 = (size_t)gy * WW + gx0;
  float inv0 = 1.f / (ws2[0] + 1e-8f);
  float inv1 = 1.f / (ws2[1] + 1e-8f);
  #pragma unroll
  for (int c = 0; c < 4; ++c) {
    float2 o = make_float2(acc[0][c] * inv0, acc[1][c] * inv1);
    *reinterpret_cast<float2*>(outdyn + (size_t)c * HWP + p0) = o;
    if (OUT && c < 3) {
      float2 al = *reinterpret_cast<const float2*>(albedo + (size_t)c * HWP + p0);
      float2 oo = make_float2(o.x * al.x, o.y * al.y);
      *reinterpret_cast<float2*>(outp + (size_t)c * HWP + p0) = oo;
    }
  }
}

extern "C" void kernel_launch(void* const* d_in, const int* in_sizes, int n_in,
                              void* d_out, int out_size, void* d_ws, size_t ws_size,
                              hipStream_t stream) {
  const float* x          = (const float*)d_in[0];
  const float* alpha      = (const float*)d_in[1];
  const float* cr_w0      = (const float*)d_in[2];
  const float* cr_b0      = (const float*)d_in[3];
  const float* cr_w1      = (const float*)d_in[4];
  const float* cr_b1      = (const float*)d_in[5];
  const float* cr_w2      = (const float*)d_in[6];
  const float* cr_b2      = (const float*)d_in[7];
  const float* hs_w0      = (const float*)d_in[8];
  const float* hs_b0      = (const float*)d_in[9];
  const float* hs_w1      = (const float*)d_in[10];
  const float* hs_b1      = (const float*)d_in[11];
  const float* hs_w2      = (const float*)d_in[12];
  const float* hs_b2      = (const float*)d_in[13];
  const float* filt_w     = (const float*)d_in[14];
  const float* filt_b     = (const float*)d_in[15];
  const float* filt_scale = (const float*)d_in[16];

  float* out = (float*)d_out;
  float* ws  = (float*)d_ws;
  const size_t P = (size_t)HWP;

  bool batched = ws_size >= (size_t)108 * P * sizeof(float);
  float *bufA, *bufB, *dynT, *dynA, *dynB, *hid;
  if (batched) {
    bufA = ws;            bufB = ws + 48 * P;
    dynT = ws + 96 * P;   dynA = ws + 100 * P;  dynB = ws + 104 * P;
  } else {
    bufA = ws;            bufB = ws + 12 * P;
    dynT = ws + 24 * P;   dynA = ws + 28 * P;   dynB = ws + 32 * P;
  }
  hid = bufA;   // CNN ping-pong dead by the time hidden is written

  const int NB8 = (WW / 128) * (HH / 8);   // 900  (PX=8 lcn)
  const int NB4 = (WW / 64)  * (HH / 8);   // 1800 (PX=4 conv)
  const int NBE = HWP / (256 * 4);         // 900
  const int NBF = (WW / 32)  * (HH / 16);  // 1800 fused filter blocks

  if (batched) {
    dim3 g8(NB8, NFRM), g4(NB4, NFRM);
    lcn_v3<<<g8, 128, 0, stream>>>(x, 12 * P, bufA, 6 * P);
    conv3x3_v3<4, 6, 0, 6,  true ><<<g4, 128, 0, stream>>>(bufA, 6 * P,  nullptr, 0, cr_w0, cr_b0, bufB, 6 * P);
    conv3x3_v3<4, 6, 0, 12, true ><<<g4, 128, 0, stream>>>(bufB, 6 * P,  nullptr, 0, cr_w1, cr_b1, bufA, 12 * P);
    conv3x3_v3<4, 12, 0, 3, false><<<g4, 128, 0, stream>>>(bufA, 12 * P, nullptr, 0, cr_w2, cr_b2, bufB, 3 * P);
    conv3x3_v3<4, 3, 9, 12, true ><<<g4, 128, 0, stream>>>(bufB, 3 * P,  x + 3 * P, 12 * P, hs_w0, hs_b0, bufA, 12 * P);
    conv3x3_v3<4, 12, 0, 12, true><<<g4, 128, 0, stream>>>(bufA, 12 * P, nullptr, 0, hs_w1, hs_b1, bufB, 12 * P);
    conv3x3_v3<4, 12, 0, 1, false><<<g4, 128, 0, stream>>>(bufB, 12 * P, nullptr, 0, hs_w2, hs_b2, hid, P);
  }

  for (int f = 0; f < NFRM; ++f) {
    const float* frame  = x + (size_t)f * 12 * P;
    const float* fixedp = frame + 3 * P;

    if (!batched) {
      dim3 g8(NB8, 1), g4(NB4, 1);
      lcn_v3<<<g8, 128, 0, stream>>>(frame, 0, bufA, 0);
      conv3x3_v3<4, 6, 0, 6,  true ><<<g4, 128, 0, stream>>>(bufA, 0, nullptr, 0, cr_w0, cr_b0, bufB, 0);
      conv3x3_v3<4, 6, 0, 12, true ><<<g4, 128, 0, stream>>>(bufB, 0, nullptr, 0, cr_w1, cr_b1, bufA, 0);
      conv3x3_v3<4, 12, 0, 3, false><<<g4, 128, 0, stream>>>(bufA, 0, nullptr, 0, cr_w2, cr_b2, bufB, 0);
      conv3x3_v3<4, 3, 9, 12, true ><<<g4, 128, 0, stream>>>(bufB, 0, fixedp, 0, hs_w0, hs_b0, bufA, 0);
      conv3x3_v3<4, 12, 0, 12, true><<<g4, 128, 0, stream>>>(bufA, 0, nullptr, 0, hs_w1, hs_b1, bufB, 0);
      conv3x3_v3<4, 12, 0, 1, false><<<g4, 128, 0, stream>>>(bufB, 0, nullptr, 0, hs_w2, hs_b2, hid, 0);
    }

    const float* hidf = batched ? (hid + (size_t)f * P) : hid;
    blend_v3<<<NBE, 256, 0, stream>>>(frame, hidf, dynT, alpha, dynA, f == 0 ? 1 : 0);

    float* cur = dynA;
    float* nxt = dynB;
    for (int k = 0; k < 5; ++k) {
      const float* wk = filt_w + (size_t)k * 8 * 13 * 9;
      const float* bk = filt_b + k * 8;
      const float* sk = filt_scale + k * 8;
      if (k < 4) {
        filt_fused<false><<<NBF, 256, 0, stream>>>(cur, fixedp, wk, bk, sk, nxt,
                                                   nullptr, nullptr);
        float* t = cur; cur = nxt; nxt = t;
      } else {
        filt_fused<true><<<NBF, 256, 0, stream>>>(cur, fixedp, wk, bk, sk, dynT,
                                                  fixedp, out + (size_t)f * 3 * P);
      }
    }
  }
}